// Round 1
// baseline (1160.070 us; speedup 1.0000x reference)
//
#include <hip/hip_runtime.h>
#include <math.h>

// B=32, S=2048, D=512, R=4, H=32. Tokens = 65536. Tile = 64 tokens.
#define NTOK 65536
#define TOK 64
#define NTILE 1024

__device__ __forceinline__ float sigmoid_fast(float x) {
    return __builtin_amdgcn_rcpf(1.0f + __expf(-x));
}

// ---------------------------------------------------------------------------
// Kernel 1: router. Per 64-token tile: h1 = relu(x@rw1^T+b), h2 = relu(h1@rw2^T+b),
// logits = h2@rw3^T+b, softmax -> probs, std -> uncertainty.
// ---------------------------------------------------------------------------
__global__ __launch_bounds__(256, 2) void k_router(
    const float* __restrict__ x,
    const float* __restrict__ rw1, const float* __restrict__ rb1,
    const float* __restrict__ rw2, const float* __restrict__ rb2,
    const float* __restrict__ rw3, const float* __restrict__ rb3,
    float* __restrict__ probs_out, float* __restrict__ unc_out)
{
    __shared__ float XsT[32][68];    // [k][tok]
    __shared__ float WsT[32][132];   // [k][out 0..127]
    __shared__ float H1[64][132];    // [tok][128]
    __shared__ float H2[64][68];     // [tok][64]

    const int tid = threadIdx.x;
    const int tx = tid & 15, ty = tid >> 4;
    const long t0 = (long)blockIdx.x * TOK;

    float acc[4][8];
#pragma unroll
    for (int i = 0; i < 4; i++)
#pragma unroll
        for (int o = 0; o < 8; o++) acc[i][o] = 0.f;

    for (int kc = 0; kc < 16; kc++) {
        __syncthreads();
        // stage X chunk transposed: [64 tok][32 k] -> XsT[k][tok]
#pragma unroll
        for (int s = 0; s < 2; s++) {
            int id = tid + s * 256;          // 0..511
            int tok = id >> 3, kq = id & 7;
            float4 v = *(const float4*)&x[(t0 + tok) * 512 + kc * 32 + kq * 4];
            XsT[kq * 4 + 0][tok] = v.x; XsT[kq * 4 + 1][tok] = v.y;
            XsT[kq * 4 + 2][tok] = v.z; XsT[kq * 4 + 3][tok] = v.w;
        }
        // stage rw1 chunk transposed: [128 out][32 k] -> WsT[k][out]
#pragma unroll
        for (int s = 0; s < 4; s++) {
            int id = tid + s * 256;          // 0..1023
            int out = id >> 3, kq = id & 7;
            float4 v = *(const float4*)&rw1[(long)out * 512 + kc * 32 + kq * 4];
            WsT[kq * 4 + 0][out] = v.x; WsT[kq * 4 + 1][out] = v.y;
            WsT[kq * 4 + 2][out] = v.z; WsT[kq * 4 + 3][out] = v.w;
        }
        __syncthreads();
#pragma unroll
        for (int k = 0; k < 32; k++) {
            const float4 xv = *(const float4*)&XsT[k][ty * 4];
            const float4 wa = *(const float4*)&WsT[k][tx * 8];
            const float4 wb = *(const float4*)&WsT[k][tx * 8 + 4];
            const float xs[4] = {xv.x, xv.y, xv.z, xv.w};
            const float ws[8] = {wa.x, wa.y, wa.z, wa.w, wb.x, wb.y, wb.z, wb.w};
#pragma unroll
            for (int i = 0; i < 4; i++)
#pragma unroll
                for (int o = 0; o < 8; o++)
                    acc[i][o] = fmaf(xs[i], ws[o], acc[i][o]);
        }
    }

    // epilogue layer1: bias + relu -> H1 [tok][128]
#pragma unroll
    for (int o = 0; o < 8; o++) {
        float b = rb1[tx * 8 + o];
#pragma unroll
        for (int i = 0; i < 4; i++) {
            float v = acc[i][o] + b;
            H1[ty * 4 + i][tx * 8 + o] = v > 0.f ? v : 0.f;
        }
    }
    __syncthreads();

    // layer2: [64,128] @ rw2^T[128,64] -> H2
    float a2[4][4];
#pragma unroll
    for (int i = 0; i < 4; i++)
#pragma unroll
        for (int o = 0; o < 4; o++) a2[i][o] = 0.f;

    for (int k4 = 0; k4 < 32; k4++) {
        float4 hv[4], wv[4];
#pragma unroll
        for (int i = 0; i < 4; i++) hv[i] = *(const float4*)&H1[ty * 4 + i][k4 * 4];
#pragma unroll
        for (int o = 0; o < 4; o++) wv[o] = *(const float4*)&rw2[(tx * 4 + o) * 128 + k4 * 4];
#pragma unroll
        for (int i = 0; i < 4; i++)
#pragma unroll
            for (int o = 0; o < 4; o++)
                a2[i][o] += hv[i].x * wv[o].x + hv[i].y * wv[o].y +
                            hv[i].z * wv[o].z + hv[i].w * wv[o].w;
    }
#pragma unroll
    for (int o = 0; o < 4; o++) {
        float b = rb2[tx * 4 + o];
#pragma unroll
        for (int i = 0; i < 4; i++) {
            float v = a2[i][o] + b;
            H2[ty * 4 + i][tx * 4 + o] = v > 0.f ? v : 0.f;
        }
    }
    __syncthreads();

    // layer3 + softmax + std: one thread per token
    if (tid < 64) {
        int tok = tid;
        float lg[4];
#pragma unroll
        for (int r = 0; r < 4; r++) {
            float s = rb3[r];
            for (int k4 = 0; k4 < 16; k4++) {
                float4 h = *(const float4*)&H2[tok][k4 * 4];
                float4 w = *(const float4*)&rw3[r * 64 + k4 * 4];
                s += h.x * w.x + h.y * w.y + h.z * w.z + h.w * w.w;
            }
            lg[r] = s;
        }
        float m = fmaxf(fmaxf(lg[0], lg[1]), fmaxf(lg[2], lg[3]));
        float e0 = __expf(lg[0] - m), e1 = __expf(lg[1] - m);
        float e2 = __expf(lg[2] - m), e3 = __expf(lg[3] - m);
        float inv = __builtin_amdgcn_rcpf(e0 + e1 + e2 + e3);
        float p0 = e0 * inv, p1 = e1 * inv, p2 = e2 * inv, p3 = e3 * inv;
        *(float4*)&probs_out[(t0 + tok) * 4] = make_float4(p0, p1, p2, p3);
        float mean = 0.25f * (p0 + p1 + p2 + p3);
        float d0 = p0 - mean, d1 = p1 - mean, d2 = p2 - mean, d3 = p3 - mean;
        unc_out[t0 + tok] = sqrtf((d0 * d0 + d1 * d1 + d2 * d2 + d3 * d3) * (1.f / 3.f));
    }
}

// ---------------------------------------------------------------------------
// Kernel 2: blocks 0..31 run the GRU (1 wave per batch, shuffle-based);
// blocks 32..1055 run the experts + weighted mixture for tile (blockIdx-32).
// ---------------------------------------------------------------------------
__global__ __launch_bounds__(256, 2) void k_experts_gru(
    const float* __restrict__ x,
    const float* __restrict__ ew1, const float* __restrict__ eb1,
    const float* __restrict__ ew2, const float* __restrict__ eb2,
    const float* __restrict__ probs, float* __restrict__ weighted_out,
    const float* __restrict__ gwih, const float* __restrict__ gwhh,
    const float* __restrict__ gbih, const float* __restrict__ gbhh,
    float* __restrict__ trans_out)
{
    if (blockIdx.x < 32) {
        // ------------------------- GRU path -------------------------
        if (threadIdx.x >= 64) return;
        const int b = blockIdx.x;
        const int l = threadIdx.x;
        const int j = l & 31, half = l >> 5;

        float whh[3][16];
#pragma unroll
        for (int g = 0; g < 3; g++)
#pragma unroll
            for (int kk = 0; kk < 16; kk++)
                whh[g][kk] = gwhh[(j + 32 * g) * 32 + half * 16 + kk];
        float wih[3][4];
#pragma unroll
        for (int g = 0; g < 3; g++)
#pragma unroll
            for (int r = 0; r < 4; r++)
                wih[g][r] = gwih[(j + 32 * g) * 4 + r];
        const float brz0 = gbih[j] + gbhh[j];
        const float brz1 = gbih[j + 32] + gbhh[j + 32];
        const float bin = gbih[j + 64], bhn = gbhh[j + 64];

        const float* pb = probs + (long)b * 2048 * 4;
        float h = 0.f;
        float4 p = *(const float4*)pb;
        for (int t = 0; t < 2048; t++) {
            float4 pn = (t < 2047) ? *(const float4*)(pb + (t + 1) * 4) : p;
            float gi0 = wih[0][0] * p.x + wih[0][1] * p.y + wih[0][2] * p.z + wih[0][3] * p.w;
            float gi1 = wih[1][0] * p.x + wih[1][1] * p.y + wih[1][2] * p.z + wih[1][3] * p.w;
            float gi2 = wih[2][0] * p.x + wih[2][1] * p.y + wih[2][2] * p.z + wih[2][3] * p.w;
            float a0 = 0.f, a1 = 0.f, a2 = 0.f;
#pragma unroll
            for (int kk = 0; kk < 16; kk++) {
                float hb = __shfl(h, half * 16 + kk);
                a0 = fmaf(whh[0][kk], hb, a0);
                a1 = fmaf(whh[1][kk], hb, a1);
                a2 = fmaf(whh[2][kk], hb, a2);
            }
            a0 += __shfl_xor(a0, 32);
            a1 += __shfl_xor(a1, 32);
            a2 += __shfl_xor(a2, 32);
            float r = sigmoid_fast(gi0 + brz0 + a0);
            float z = sigmoid_fast(gi1 + brz1 + a1);
            float nx = gi2 + bin + r * (a2 + bhn);
            nx = fminf(fmaxf(nx, -15.f), 15.f);
            float e2x = __expf(-2.f * nx);
            float n = (1.f - e2x) * __builtin_amdgcn_rcpf(1.f + e2x);
            h = (1.f - z) * n + z * h;
            if (l < 32) trans_out[((long)b * 2048 + t) * 32 + j] = h;
            p = pn;
        }
        return;
    }

    // ------------------------- experts path -------------------------
    __shared__ float XsT[32][68];
    __shared__ float WsT[32][132];
    __shared__ float E1[64][132];
    __shared__ float pS[64][4];

    const int tid = threadIdx.x;
    const int tx = tid & 15, ty = tid >> 4;
    const long t0 = (long)(blockIdx.x - 32) * TOK;

    if (tid < 64) *(float4*)&pS[tid][0] = *(const float4*)&probs[(t0 + tid) * 4];

    float wacc[4][8];
#pragma unroll
    for (int i = 0; i < 4; i++)
#pragma unroll
        for (int o = 0; o < 8; o++) wacc[i][o] = 0.f;

    for (int g = 0; g < 2; g++) {   // regime pairs {0,1}, {2,3}
        float acc[4][8];
#pragma unroll
        for (int i = 0; i < 4; i++)
#pragma unroll
            for (int o = 0; o < 8; o++) acc[i][o] = 0.f;

        for (int kc = 0; kc < 16; kc++) {
            __syncthreads();
#pragma unroll
            for (int s = 0; s < 2; s++) {
                int id = tid + s * 256;
                int tok = id >> 3, kq = id & 7;
                float4 v = *(const float4*)&x[(t0 + tok) * 512 + kc * 32 + kq * 4];
                XsT[kq * 4 + 0][tok] = v.x; XsT[kq * 4 + 1][tok] = v.y;
                XsT[kq * 4 + 2][tok] = v.z; XsT[kq * 4 + 3][tok] = v.w;
            }
#pragma unroll
            for (int s = 0; s < 4; s++) {
                int id = tid + s * 256;
                int out = id >> 3, kq = id & 7;
                float4 v = *(const float4*)&ew1[(long)(g * 128 + out) * 512 + kc * 32 + kq * 4];
                WsT[kq * 4 + 0][out] = v.x; WsT[kq * 4 + 1][out] = v.y;
                WsT[kq * 4 + 2][out] = v.z; WsT[kq * 4 + 3][out] = v.w;
            }
            __syncthreads();
#pragma unroll
            for (int k = 0; k < 32; k++) {
                const float4 xv = *(const float4*)&XsT[k][ty * 4];
                const float4 wa = *(const float4*)&WsT[k][tx * 8];
                const float4 wb = *(const float4*)&WsT[k][tx * 8 + 4];
                const float xs[4] = {xv.x, xv.y, xv.z, xv.w};
                const float ws[8] = {wa.x, wa.y, wa.z, wa.w, wb.x, wb.y, wb.z, wb.w};
#pragma unroll
                for (int i = 0; i < 4; i++)
#pragma unroll
                    for (int o = 0; o < 8; o++)
                        acc[i][o] = fmaf(xs[i], ws[o], acc[i][o]);
            }
        }
        __syncthreads();
        // e1 epilogue -> E1 [tok][128] (2 regimes of this pass)
#pragma unroll
        for (int o = 0; o < 8; o++) {
            float b = eb1[g * 128 + tx * 8 + o];
#pragma unroll
            for (int i = 0; i < 4; i++) {
                float v = acc[i][o] + b;
                E1[ty * 4 + i][tx * 8 + o] = v > 0.f ? v : 0.f;
            }
        }
        __syncthreads();

        // layer2 per regime: K=64. Thread covers [4 tok][8 outs of 128].
        const int rl = tx >> 3;            // 0/1 -> regime within pass
        const int fb = (tx & 7) * 8;       // feature base 0..56
        const int rg = g * 2 + rl;         // global regime

        float a2[4][8];
#pragma unroll
        for (int i = 0; i < 4; i++)
#pragma unroll
            for (int o = 0; o < 8; o++) a2[i][o] = 0.f;

        for (int k4 = 0; k4 < 16; k4++) {
            float4 hv[4];
#pragma unroll
            for (int i = 0; i < 4; i++)
                hv[i] = *(const float4*)&E1[ty * 4 + i][rl * 64 + k4 * 4];
#pragma unroll
            for (int o = 0; o < 8; o++) {
                float4 wv = *(const float4*)&ew2[(long)(rg * 64 + fb + o) * 64 + k4 * 4];
#pragma unroll
                for (int i = 0; i < 4; i++)
                    a2[i][o] += hv[i].x * wv.x + hv[i].y * wv.y +
                                hv[i].z * wv.z + hv[i].w * wv.w;
            }
        }
        // weighted accumulate: wacc += p[tok][rg] * relu(a2 + eb2)
        float pr[4];
#pragma unroll
        for (int i = 0; i < 4; i++) pr[i] = pS[ty * 4 + i][rg];
#pragma unroll
        for (int o = 0; o < 8; o++) {
            float b = eb2[rg * 64 + fb + o];
#pragma unroll
            for (int i = 0; i < 4; i++) {
                float v = a2[i][o] + b;
                v = v > 0.f ? v : 0.f;
                wacc[i][o] = fmaf(pr[i], v, wacc[i][o]);
            }
        }
        __syncthreads();  // protect E1 before next pass overwrites
    }

    // reduce regimes across lane pairs (tx ^ 8) and store weighted
#pragma unroll
    for (int i = 0; i < 4; i++)
#pragma unroll
        for (int o = 0; o < 8; o++)
            wacc[i][o] += __shfl_xor(wacc[i][o], 8);

    if ((tx & 8) == 0) {
#pragma unroll
        for (int i = 0; i < 4; i++) {
            float4 v0 = make_float4(wacc[i][0], wacc[i][1], wacc[i][2], wacc[i][3]);
            float4 v1 = make_float4(wacc[i][4], wacc[i][5], wacc[i][6], wacc[i][7]);
            long base = (t0 + ty * 4 + i) * 64 + (tx & 7) * 8;
            *(float4*)&weighted_out[base] = v0;
            *(float4*)&weighted_out[base + 4] = v1;
        }
    }
}

extern "C" void kernel_launch(void* const* d_in, const int* in_sizes, int n_in,
                              void* d_out, int out_size, void* d_ws, size_t ws_size,
                              hipStream_t stream) {
    const float* x    = (const float*)d_in[0];
    const float* rw1  = (const float*)d_in[1];
    const float* rb1  = (const float*)d_in[2];
    const float* rw2  = (const float*)d_in[3];
    const float* rb2  = (const float*)d_in[4];
    const float* rw3  = (const float*)d_in[5];
    const float* rb3  = (const float*)d_in[6];
    const float* ew1  = (const float*)d_in[7];
    const float* eb1  = (const float*)d_in[8];
    const float* ew2  = (const float*)d_in[9];
    const float* eb2  = (const float*)d_in[10];
    const float* gwih = (const float*)d_in[11];
    const float* gwhh = (const float*)d_in[12];
    const float* gbih = (const float*)d_in[13];
    const float* gbhh = (const float*)d_in[14];

    float* out        = (float*)d_out;
    float* probs_o    = out;                         // 32*2048*4
    float* weighted_o = out + 262144;                // 32*2048*64
    float* trans_o    = out + 262144 + 4194304;      // 32*2048*32
    float* unc_o      = trans_o + 2097152;           // 32*2048

    hipLaunchKernelGGL(k_router, dim3(NTILE), dim3(256), 0, stream,
                       x, rw1, rb1, rw2, rb2, rw3, rb3, probs_o, unc_o);
    hipLaunchKernelGGL(k_experts_gru, dim3(NTILE + 32), dim3(256), 0, stream,
                       x, ew1, eb1, ew2, eb2, probs_o, weighted_o,
                       gwih, gwhh, gbih, gbhh, trans_o);
}

// Round 2
// 818.455 us; speedup vs baseline: 1.4174x; 1.4174x over previous
//
#include <hip/hip_runtime.h>
#include <math.h>

// B=32, S=2048, D=512, R=4, H=32. Tokens = 65536. Tile = 64 tokens.
#define NTOK 65536
#define TOK 64
#define NTILE 1024

// ---------------------------------------------------------------------------
// Kernel 1: router. Per 64-token tile: h1 = relu(x@rw1^T+b), h2 = relu(h1@rw2^T+b),
// logits = h2@rw3^T+b, softmax -> probs, std -> uncertainty.
// ---------------------------------------------------------------------------
__global__ __launch_bounds__(256, 2) void k_router(
    const float* __restrict__ x,
    const float* __restrict__ rw1, const float* __restrict__ rb1,
    const float* __restrict__ rw2, const float* __restrict__ rb2,
    const float* __restrict__ rw3, const float* __restrict__ rb3,
    float* __restrict__ probs_out, float* __restrict__ unc_out)
{
    __shared__ float XsT[32][68];    // [k][tok]
    __shared__ float WsT[32][132];   // [k][out 0..127]
    __shared__ float H1[64][132];    // [tok][128]
    __shared__ float H2[64][68];     // [tok][64]

    const int tid = threadIdx.x;
    const int tx = tid & 15, ty = tid >> 4;
    const long t0 = (long)blockIdx.x * TOK;

    float acc[4][8];
#pragma unroll
    for (int i = 0; i < 4; i++)
#pragma unroll
        for (int o = 0; o < 8; o++) acc[i][o] = 0.f;

    for (int kc = 0; kc < 16; kc++) {
        __syncthreads();
        // stage X chunk transposed: [64 tok][32 k] -> XsT[k][tok]
#pragma unroll
        for (int s = 0; s < 2; s++) {
            int id = tid + s * 256;          // 0..511
            int tok = id >> 3, kq = id & 7;
            float4 v = *(const float4*)&x[(t0 + tok) * 512 + kc * 32 + kq * 4];
            XsT[kq * 4 + 0][tok] = v.x; XsT[kq * 4 + 1][tok] = v.y;
            XsT[kq * 4 + 2][tok] = v.z; XsT[kq * 4 + 3][tok] = v.w;
        }
        // stage rw1 chunk transposed: [128 out][32 k] -> WsT[k][out]
#pragma unroll
        for (int s = 0; s < 4; s++) {
            int id = tid + s * 256;          // 0..1023
            int out = id >> 3, kq = id & 7;
            float4 v = *(const float4*)&rw1[(long)out * 512 + kc * 32 + kq * 4];
            WsT[kq * 4 + 0][out] = v.x; WsT[kq * 4 + 1][out] = v.y;
            WsT[kq * 4 + 2][out] = v.z; WsT[kq * 4 + 3][out] = v.w;
        }
        __syncthreads();
#pragma unroll
        for (int k = 0; k < 32; k++) {
            const float4 xv = *(const float4*)&XsT[k][ty * 4];
            const float4 wa = *(const float4*)&WsT[k][tx * 4];        // cols tx*4..+3
            const float4 wb = *(const float4*)&WsT[k][64 + tx * 4];   // cols 64+tx*4..+3
            const float xs[4] = {xv.x, xv.y, xv.z, xv.w};
            const float ws[8] = {wa.x, wa.y, wa.z, wa.w, wb.x, wb.y, wb.z, wb.w};
#pragma unroll
            for (int i = 0; i < 4; i++)
#pragma unroll
                for (int o = 0; o < 8; o++)
                    acc[i][o] = fmaf(xs[i], ws[o], acc[i][o]);
        }
    }

    // epilogue layer1: bias + relu -> H1 [tok][128]
#pragma unroll
    for (int o = 0; o < 8; o++) {
        const int col = (o < 4) ? (tx * 4 + o) : (64 + tx * 4 + (o - 4));
        float b = rb1[col];
#pragma unroll
        for (int i = 0; i < 4; i++) {
            float v = acc[i][o] + b;
            H1[ty * 4 + i][col] = v > 0.f ? v : 0.f;
        }
    }
    __syncthreads();

    // layer2: [64,128] @ rw2^T[128,64] -> H2
    float a2[4][4];
#pragma unroll
    for (int i = 0; i < 4; i++)
#pragma unroll
        for (int o = 0; o < 4; o++) a2[i][o] = 0.f;

    for (int k4 = 0; k4 < 32; k4++) {
        float4 hv[4], wv[4];
#pragma unroll
        for (int i = 0; i < 4; i++) hv[i] = *(const float4*)&H1[ty * 4 + i][k4 * 4];
#pragma unroll
        for (int o = 0; o < 4; o++) wv[o] = *(const float4*)&rw2[(tx * 4 + o) * 128 + k4 * 4];
#pragma unroll
        for (int i = 0; i < 4; i++)
#pragma unroll
            for (int o = 0; o < 4; o++)
                a2[i][o] += hv[i].x * wv[o].x + hv[i].y * wv[o].y +
                            hv[i].z * wv[o].z + hv[i].w * wv[o].w;
    }
#pragma unroll
    for (int o = 0; o < 4; o++) {
        float b = rb2[tx * 4 + o];
#pragma unroll
        for (int i = 0; i < 4; i++) {
            float v = a2[i][o] + b;
            H2[ty * 4 + i][tx * 4 + o] = v > 0.f ? v : 0.f;
        }
    }
    __syncthreads();

    // layer3 + softmax + std: one thread per token
    if (tid < 64) {
        int tok = tid;
        float lg[4];
#pragma unroll
        for (int r = 0; r < 4; r++) {
            float s = rb3[r];
            for (int k4 = 0; k4 < 16; k4++) {
                float4 h = *(const float4*)&H2[tok][k4 * 4];
                float4 w = *(const float4*)&rw3[r * 64 + k4 * 4];
                s += h.x * w.x + h.y * w.y + h.z * w.z + h.w * w.w;
            }
            lg[r] = s;
        }
        float m = fmaxf(fmaxf(lg[0], lg[1]), fmaxf(lg[2], lg[3]));
        float e0 = __expf(lg[0] - m), e1 = __expf(lg[1] - m);
        float e2 = __expf(lg[2] - m), e3 = __expf(lg[3] - m);
        float inv = __builtin_amdgcn_rcpf(e0 + e1 + e2 + e3);
        float p0 = e0 * inv, p1 = e1 * inv, p2 = e2 * inv, p3 = e3 * inv;
        *(float4*)&probs_out[(t0 + tok) * 4] = make_float4(p0, p1, p2, p3);
        float mean = 0.25f * (p0 + p1 + p2 + p3);
        float d0 = p0 - mean, d1 = p1 - mean, d2 = p2 - mean, d3 = p3 - mean;
        unc_out[t0 + tok] = sqrtf((d0 * d0 + d1 * d1 + d2 * d2 + d3 * d3) * (1.f / 3.f));
    }
}

// ---------------------------------------------------------------------------
// Kernel 2: blocks 0..31 run the GRU (1 wave per batch, K-split + LDS bcast);
// blocks 32..1055 run the experts + weighted mixture for tile (blockIdx-32).
// ---------------------------------------------------------------------------
__global__ __launch_bounds__(256, 2) void k_experts_gru(
    const float* __restrict__ x,
    const float* __restrict__ ew1, const float* __restrict__ eb1,
    const float* __restrict__ ew2, const float* __restrict__ eb2,
    const float* __restrict__ probs, float* __restrict__ weighted_out,
    const float* __restrict__ gwih, const float* __restrict__ gwhh,
    const float* __restrict__ gbih, const float* __restrict__ gbhh,
    float* __restrict__ trans_out)
{
    if (blockIdx.x < 32) {
        // ------------------------- GRU path -------------------------
        // One wave per batch. Lane l: j = l&31 (output index), half = l>>5
        // (K-half). Each lane holds whh[3][16] for its K-half; partial dots
        // need no cross-lane traffic; 3 shfl_xor(32) combine the halves; both
        // halves redundantly compute h_j (uniform code). Broadcast h via LDS
        // (1 write + 4 ds_read_b128), single-wave in-order DS.
        if (threadIdx.x >= 64) return;
        const int b = blockIdx.x;
        const int l = threadIdx.x;
        const int j = l & 31, half = l >> 5;
        __shared__ float hS[32];

        float whh[3][16];
#pragma unroll
        for (int g = 0; g < 3; g++) {
            const float* wp = gwhh + (j + 32 * g) * 32 + half * 16;
#pragma unroll
            for (int q = 0; q < 4; q++) {
                float4 w = *(const float4*)(wp + q * 4);
                whh[g][q * 4 + 0] = w.x; whh[g][q * 4 + 1] = w.y;
                whh[g][q * 4 + 2] = w.z; whh[g][q * 4 + 3] = w.w;
            }
        }
        float wih[3][4];
#pragma unroll
        for (int g = 0; g < 3; g++) {
            float4 w = *(const float4*)&gwih[(j + 32 * g) * 4];
            wih[g][0] = w.x; wih[g][1] = w.y; wih[g][2] = w.z; wih[g][3] = w.w;
        }
        const float bR = gbih[j] + gbhh[j];
        const float bZ = gbih[j + 32] + gbhh[j + 32];
        const float bIN = gbih[j + 64], bHN = gbhh[j + 64];

        const float* pb = probs + (long)b * 2048 * 4;
        float4 p0 = *(const float4*)pb;
        float4 p1 = *(const float4*)(pb + 4);
        float hk[16];
#pragma unroll
        for (int k = 0; k < 16; k++) hk[k] = 0.f;
        float hj = 0.f;
        float* tr = trans_out + (long)b * 2048 * 32 + j;

        for (int t = 0; t < 2048; t++) {
            const int tn = (t + 2 < 2047) ? (t + 2) : 2047;
            float4 p2 = *(const float4*)(pb + tn * 4);     // prefetch distance 2

            // partial matvec over this lane's K-half (48 fma, 6 chains)
            float aR0 = 0.f, aR1 = 0.f, aZ0 = 0.f, aZ1 = 0.f, aN0 = 0.f, aN1 = 0.f;
#pragma unroll
            for (int k = 0; k < 16; k += 2) {
                aR0 = fmaf(whh[0][k],     hk[k],     aR0);
                aR1 = fmaf(whh[0][k + 1], hk[k + 1], aR1);
                aZ0 = fmaf(whh[1][k],     hk[k],     aZ0);
                aZ1 = fmaf(whh[1][k + 1], hk[k + 1], aZ1);
                aN0 = fmaf(whh[2][k],     hk[k],     aN0);
                aN1 = fmaf(whh[2][k + 1], hk[k + 1], aN1);
            }
            float aR = aR0 + aR1, aZ = aZ0 + aZ1, aN = aN0 + aN1;
            aR += __shfl_xor(aR, 32);
            aZ += __shfl_xor(aZ, 32);
            aN += __shfl_xor(aN, 32);

            // input-gate dots (independent of h -> overlaps shfl latency)
            float giR = fmaf(wih[0][3], p0.w, fmaf(wih[0][2], p0.z,
                        fmaf(wih[0][1], p0.y, fmaf(wih[0][0], p0.x, bR))));
            float giZ = fmaf(wih[1][3], p0.w, fmaf(wih[1][2], p0.z,
                        fmaf(wih[1][1], p0.y, fmaf(wih[1][0], p0.x, bZ))));
            float giN = fmaf(wih[2][3], p0.w, fmaf(wih[2][2], p0.z,
                        fmaf(wih[2][1], p0.y, fmaf(wih[2][0], p0.x, bIN))));

            float r = __builtin_amdgcn_rcpf(1.f + __expf(-(giR + aR)));
            float z = __builtin_amdgcn_rcpf(1.f + __expf(-(giZ + aZ)));
            float nx = giN + r * (aN + bHN);      // |nx| <= ~7, no clamp needed
            float n = fmaf(2.f, __builtin_amdgcn_rcpf(1.f + __expf(-2.f * nx)), -1.f);
            hj = fmaf(z, hj - n, n);              // (1-z)*n + z*h

            if (l < 32) tr[t * 32] = hj;
            hS[j] = hj;                            // lanes j and j+32 write same value
            asm volatile("s_waitcnt lgkmcnt(0)" ::: "memory");
#pragma unroll
            for (int q = 0; q < 4; q++) {
                float4 h4 = *(const float4*)&hS[half * 16 + q * 4];
                hk[q * 4 + 0] = h4.x; hk[q * 4 + 1] = h4.y;
                hk[q * 4 + 2] = h4.z; hk[q * 4 + 3] = h4.w;
            }
            p0 = p1; p1 = p2;
        }
        return;
    }

    // ------------------------- experts path -------------------------
    __shared__ float XsT[32][68];
    __shared__ float WsT[32][132];
    __shared__ float E1[64][132];
    __shared__ float pS[64][4];

    const int tid = threadIdx.x;
    const int tx = tid & 15, ty = tid >> 4;
    const long t0 = (long)(blockIdx.x - 32) * TOK;

    if (tid < 64) *(float4*)&pS[tid][0] = *(const float4*)&probs[(t0 + tid) * 4];

    float wacc[4][8];
#pragma unroll
    for (int i = 0; i < 4; i++)
#pragma unroll
        for (int o = 0; o < 8; o++) wacc[i][o] = 0.f;

    for (int g = 0; g < 2; g++) {   // regime pairs {0,1}, {2,3}
        float acc[4][8];
#pragma unroll
        for (int i = 0; i < 4; i++)
#pragma unroll
            for (int o = 0; o < 8; o++) acc[i][o] = 0.f;

        for (int kc = 0; kc < 16; kc++) {
            __syncthreads();
#pragma unroll
            for (int s = 0; s < 2; s++) {
                int id = tid + s * 256;
                int tok = id >> 3, kq = id & 7;
                float4 v = *(const float4*)&x[(t0 + tok) * 512 + kc * 32 + kq * 4];
                XsT[kq * 4 + 0][tok] = v.x; XsT[kq * 4 + 1][tok] = v.y;
                XsT[kq * 4 + 2][tok] = v.z; XsT[kq * 4 + 3][tok] = v.w;
            }
#pragma unroll
            for (int s = 0; s < 4; s++) {
                int id = tid + s * 256;
                int out = id >> 3, kq = id & 7;
                float4 v = *(const float4*)&ew1[(long)(g * 128 + out) * 512 + kc * 32 + kq * 4];
                WsT[kq * 4 + 0][out] = v.x; WsT[kq * 4 + 1][out] = v.y;
                WsT[kq * 4 + 2][out] = v.z; WsT[kq * 4 + 3][out] = v.w;
            }
            __syncthreads();
#pragma unroll
            for (int k = 0; k < 32; k++) {
                const float4 xv = *(const float4*)&XsT[k][ty * 4];
                const float4 wa = *(const float4*)&WsT[k][tx * 4];
                const float4 wb = *(const float4*)&WsT[k][64 + tx * 4];
                const float xs[4] = {xv.x, xv.y, xv.z, xv.w};
                const float ws[8] = {wa.x, wa.y, wa.z, wa.w, wb.x, wb.y, wb.z, wb.w};
#pragma unroll
                for (int i = 0; i < 4; i++)
#pragma unroll
                    for (int o = 0; o < 8; o++)
                        acc[i][o] = fmaf(xs[i], ws[o], acc[i][o]);
            }
        }
        __syncthreads();
        // e1 epilogue -> E1 [tok][128] (2 regimes of this pass)
#pragma unroll
        for (int o = 0; o < 8; o++) {
            const int col = (o < 4) ? (tx * 4 + o) : (64 + tx * 4 + (o - 4));
            float b = eb1[g * 128 + col];
#pragma unroll
            for (int i = 0; i < 4; i++) {
                float v = acc[i][o] + b;
                E1[ty * 4 + i][col] = v > 0.f ? v : 0.f;
            }
        }
        __syncthreads();

        // layer2 per regime: K=64. Thread covers [4 tok][8 outs of 128].
        const int rl = tx >> 3;            // 0/1 -> regime within pass
        const int fb = (tx & 7) * 8;       // feature base 0..56
        const int rg = g * 2 + rl;         // global regime

        float a2[4][8];
#pragma unroll
        for (int i = 0; i < 4; i++)
#pragma unroll
            for (int o = 0; o < 8; o++) a2[i][o] = 0.f;

        for (int k4 = 0; k4 < 16; k4++) {
            float4 hv[4];
#pragma unroll
            for (int i = 0; i < 4; i++)
                hv[i] = *(const float4*)&E1[ty * 4 + i][rl * 64 + k4 * 4];
#pragma unroll
            for (int o = 0; o < 8; o++) {
                float4 wv = *(const float4*)&ew2[(long)(rg * 64 + fb + o) * 64 + k4 * 4];
#pragma unroll
                for (int i = 0; i < 4; i++)
                    a2[i][o] += hv[i].x * wv.x + hv[i].y * wv.y +
                                hv[i].z * wv.z + hv[i].w * wv.w;
            }
        }
        // weighted accumulate: wacc += p[tok][rg] * relu(a2 + eb2)
        float pr[4];
#pragma unroll
        for (int i = 0; i < 4; i++) pr[i] = pS[ty * 4 + i][rg];
#pragma unroll
        for (int o = 0; o < 8; o++) {
            float b = eb2[rg * 64 + fb + o];
#pragma unroll
            for (int i = 0; i < 4; i++) {
                float v = a2[i][o] + b;
                v = v > 0.f ? v : 0.f;
                wacc[i][o] = fmaf(pr[i], v, wacc[i][o]);
            }
        }
        __syncthreads();  // protect E1 before next pass overwrites
    }

    // reduce regimes across lane pairs (tx ^ 8) and store weighted
#pragma unroll
    for (int i = 0; i < 4; i++)
#pragma unroll
        for (int o = 0; o < 8; o++)
            wacc[i][o] += __shfl_xor(wacc[i][o], 8);

    if ((tx & 8) == 0) {
#pragma unroll
        for (int i = 0; i < 4; i++) {
            float4 v0 = make_float4(wacc[i][0], wacc[i][1], wacc[i][2], wacc[i][3]);
            float4 v1 = make_float4(wacc[i][4], wacc[i][5], wacc[i][6], wacc[i][7]);
            long base = (t0 + ty * 4 + i) * 64 + (tx & 7) * 8;
            *(float4*)&weighted_out[base] = v0;
            *(float4*)&weighted_out[base + 4] = v1;
        }
    }
}

extern "C" void kernel_launch(void* const* d_in, const int* in_sizes, int n_in,
                              void* d_out, int out_size, void* d_ws, size_t ws_size,
                              hipStream_t stream) {
    const float* x    = (const float*)d_in[0];
    const float* rw1  = (const float*)d_in[1];
    const float* rb1  = (const float*)d_in[2];
    const float* rw2  = (const float*)d_in[3];
    const float* rb2  = (const float*)d_in[4];
    const float* rw3  = (const float*)d_in[5];
    const float* rb3  = (const float*)d_in[6];
    const float* ew1  = (const float*)d_in[7];
    const float* eb1  = (const float*)d_in[8];
    const float* ew2  = (const float*)d_in[9];
    const float* eb2  = (const float*)d_in[10];
    const float* gwih = (const float*)d_in[11];
    const float* gwhh = (const float*)d_in[12];
    const float* gbih = (const float*)d_in[13];
    const float* gbhh = (const float*)d_in[14];

    float* out        = (float*)d_out;
    float* probs_o    = out;                         // 32*2048*4
    float* weighted_o = out + 262144;                // 32*2048*64
    float* trans_o    = out + 262144 + 4194304;      // 32*2048*32
    float* unc_o      = trans_o + 2097152;           // 32*2048

    hipLaunchKernelGGL(k_router, dim3(NTILE), dim3(256), 0, stream,
                       x, rw1, rb1, rw2, rb2, rw3, rb3, probs_o, unc_o);
    hipLaunchKernelGGL(k_experts_gru, dim3(NTILE + 32), dim3(256), 0, stream,
                       x, ew1, eb1, ew2, eb2, probs_o, weighted_o,
                       gwih, gwhh, gbih, gbhh, trans_o);
}